// Round 15
// baseline (197.002 us; speedup 1.0000x reference)
//
#include <hip/hip_runtime.h>
#include <math.h>

#define D_MODEL 256
#define NHEADS 8
#define HDIM 32
#define BATCH 8
#define SEQL 4096
#define EPS 1e-6f

typedef _Float16 f16;
typedef _Float16 f16x2 __attribute__((ext_vector_type(2)));
typedef _Float16 f16x4 __attribute__((ext_vector_type(4)));
typedef _Float16 f16x8 __attribute__((ext_vector_type(8)));
typedef float f32x4 __attribute__((ext_vector_type(4)));

__device__ __forceinline__ float elu1(float x) {
    return x > 0.f ? x + 1.f : __expf(x);
}

// ---------------------------------------------------------------------------
// prep v3: weights to fp16 in FRAGMENT-LINEAR (wfrag) layout (1 KB/wave frag).
// Mats 0-2 (q,k,v) row-permuted to head-major o' = h*32+d; mat 3 (Wm)
// column-permuted.  (unchanged, verified)
// ---------------------------------------------------------------------------
__global__ void prep_kernel(const float* __restrict__ Wq, const float* __restrict__ Wk,
                            const float* __restrict__ Wv, const float* __restrict__ Wm,
                            const float* __restrict__ bq, const float* __restrict__ bk,
                            const float* __restrict__ bv,
                            f16* __restrict__ w16, float* __restrict__ bperm) {
    const int bid = blockIdx.x;
    if (bid < 1024) {
        int idx = bid * 256 + threadIdx.x;
        int mat = idx >> 16;
        int r = idx & 65535;
        int e = r & 7;
        int lane = (r >> 3) & 63;
        int kstep = (r >> 9) & 7;
        int ostrip = r >> 12;
        int o = ostrip * 16 + (lane & 15);
        int k = kstep * 32 + (lane >> 4) * 8 + e;
        const float* W = (mat == 0) ? Wq : (mat == 1) ? Wk : (mat == 2) ? Wv : Wm;
        float v;
        if (mat < 3) v = W[(size_t)(((o & 31) << 3) + (o >> 5)) * 256 + k];
        else         v = W[(size_t)o * 256 + (((k & 31) << 3) + (k >> 5))];
        w16[idx] = (f16)v;
    } else {
        int t = threadIdx.x;
        bperm[0 * 256 + t] = bq[((t & 31) << 3) + (t >> 5)];
        bperm[1 * 256 + t] = bk[((t & 31) << 3) + (t >> 5)];
        bperm[2 * 256 + t] = bv[((t & 31) << 3) + (t >> 5)];
    }
}

// ---------------------------------------------------------------------------
// gemm_fused: per (b, 64-l slice) block, three sequential GEMM phases
// (k, v, q) using the verified r10 stage-once structure over two ping-pong
// LDS buffers.  k' and v' never leave the block: KV 32x32 per head computed
// locally via MFMA (kv_mfma's verified convention), ksum via shfl (r3
// pattern), partials stored per l-slice (NO atomics).  Only q' goes to HBM.
// Saves 33 MB kp/vp writes + 33 MB re-reads + the kv_mfma kernel.
// LDS 2 x 33792 B -> 2 blocks/CU.
// ---------------------------------------------------------------------------
#define XSTR 264
#define KVS 66
#define NSPLIT 64
__global__ __launch_bounds__(256, 2) void gemm_fused(
    const float* __restrict__ Xq, const float* __restrict__ Xk, const float* __restrict__ Xv,
    const f16* __restrict__ w16, const float* __restrict__ bperm,
    f16* __restrict__ qp, float* __restrict__ KVpart, float* __restrict__ ksum_part) {
    __shared__ __align__(16) f16 BufA[64 * XSTR];   // 33792 B
    __shared__ __align__(16) f16 BufB[64 * XSTR];   // 33792 B

    const int b = blockIdx.z;
    const int ls = blockIdx.x;          // l-slice 0..63
    const int l0 = ls * 64;
    const int tid = threadIdx.x;
    const int wave = tid >> 6, lane = tid & 63;
    const int ln = lane & 15, quad = lane >> 4;
    const int kq = tid >> 4;            // chunk-k rows (4 rows x 256B per instr)
    const int lg = tid & 15;

    const size_t xoff = ((size_t)(b * D_MODEL) + 4 * kq) * SEQL + l0 + 4 * lg;

    float4 xa[4], xb[4];

#define LOADX(DST, XP, C) do { \
        const float* xp_ = (XP) + xoff + (size_t)(64 * (C)) * SEQL; \
        DST[0] = *(const float4*)(xp_ + 0 * SEQL); \
        DST[1] = *(const float4*)(xp_ + 1 * SEQL); \
        DST[2] = *(const float4*)(xp_ + 2 * SEQL); \
        DST[3] = *(const float4*)(xp_ + 3 * SEQL); \
    } while (0)

#define STOREB(SRC, BUF, C) do { \
        f16x4 w_; \
        w_[0] = (f16)SRC[0].x; w_[1] = (f16)SRC[1].x; w_[2] = (f16)SRC[2].x; w_[3] = (f16)SRC[3].x; \
        *(f16x4*)&BUF[(4 * lg + 0) * XSTR + 64 * (C) + 4 * kq] = w_; \
        w_[0] = (f16)SRC[0].y; w_[1] = (f16)SRC[1].y; w_[2] = (f16)SRC[2].y; w_[3] = (f16)SRC[3].y; \
        *(f16x4*)&BUF[(4 * lg + 1) * XSTR + 64 * (C) + 4 * kq] = w_; \
        w_[0] = (f16)SRC[0].z; w_[1] = (f16)SRC[1].z; w_[2] = (f16)SRC[2].z; w_[3] = (f16)SRC[3].z; \
        *(f16x4*)&BUF[(4 * lg + 2) * XSTR + 64 * (C) + 4 * kq] = w_; \
        w_[0] = (f16)SRC[0].w; w_[1] = (f16)SRC[1].w; w_[2] = (f16)SRC[2].w; w_[3] = (f16)SRC[3].w; \
        *(f16x4*)&BUF[(4 * lg + 3) * XSTR + 64 * (C) + 4 * kq] = w_; \
    } while (0)

#define STAGE(XP, BUF) do { \
        LOADX(xa, XP, 0); \
        LOADX(xb, XP, 1); \
        STOREB(xa, BUF, 0); \
        LOADX(xa, XP, 2); \
        STOREB(xb, BUF, 1); \
        LOADX(xb, XP, 3); \
        STOREB(xa, BUF, 2); \
        STOREB(xb, BUF, 3); \
    } while (0)

    f32x4 acc[4][4];
#define ZEROACC() do { \
        _Pragma("unroll") for (int mf = 0; mf < 4; ++mf) \
        _Pragma("unroll") for (int nf = 0; nf < 4; ++nf) \
        _Pragma("unroll") for (int r = 0; r < 4; ++r) acc[mf][nf][r] = 0.f; \
    } while (0)

#define COMPUTE(BUF, WMAT) do { \
        const f16* Wl = (WMAT) + lane * 8; \
        f16x8 afc[4], afn[4]; \
        _Pragma("unroll") for (int mf = 0; mf < 4; ++mf) \
            afc[mf] = *(const f16x8*)(Wl + (wave * 32 + mf * 8 + 0) * 512); \
        _Pragma("unroll") for (int s = 0; s < 8; ++s) { \
            const int k0 = s * 32; \
            if (s < 7) { \
                _Pragma("unroll") for (int mf = 0; mf < 4; ++mf) \
                    afn[mf] = *(const f16x8*)(Wl + (wave * 32 + mf * 8 + s + 1) * 512); \
            } \
            f16x8 bf[4]; \
            _Pragma("unroll") for (int nf = 0; nf < 4; ++nf) \
                bf[nf] = *(const f16x8*)&BUF[(nf * 16 + ln) * XSTR + k0 + quad * 8]; \
            _Pragma("unroll") for (int mf = 0; mf < 4; ++mf) \
            _Pragma("unroll") for (int nf = 0; nf < 4; ++nf) \
                acc[mf][nf] = __builtin_amdgcn_mfma_f32_16x16x32_f16(afc[mf], bf[nf], acc[mf][nf], 0, 0, 0); \
            _Pragma("unroll") for (int mf = 0; mf < 4; ++mf) afc[mf] = afn[mf]; \
        } \
    } while (0)

    // ---------------- phase k ----------------
    STAGE(Xk, BufA);
    __syncthreads();                     // BufA(Xk) ready
    ZEROACC();
    COMPUTE(BufA, w16 + 65536);
    {
        // elu1(k'+bias) -> kT (BufB rows o=channel), ksum partial via shfl
        const float* bpk = bperm + 256;
        float sp[4][4];
#pragma unroll
        for (int mf = 0; mf < 4; ++mf)
#pragma unroll
            for (int r = 0; r < 4; ++r) {
                const int o = wave * 64 + mf * 16 + quad * 4 + r;
                const float bb = bpk[o];
                float s = 0.f;
#pragma unroll
                for (int nf = 0; nf < 4; ++nf) {
                    const int l = nf * 16 + ln;
                    const float e = elu1(acc[mf][nf][r] + bb);
                    s += e;
                    BufB[o * KVS + l] = (f16)e;
                }
                sp[mf][r] = s;
            }
#pragma unroll
        for (int st = 1; st < 16; st <<= 1)
#pragma unroll
            for (int mf = 0; mf < 4; ++mf)
#pragma unroll
                for (int r = 0; r < 4; ++r)
                    sp[mf][r] += __shfl_xor(sp[mf][r], st);
        if (ln == 0) {
#pragma unroll
            for (int mf = 0; mf < 4; ++mf)
#pragma unroll
                for (int r = 0; r < 4; ++r) {
                    const int o = wave * 64 + mf * 16 + quad * 4 + r;
                    ksum_part[((size_t)ls * 64 + b * NHEADS + (o >> 5)) * 32 + (o & 31)] = sp[mf][r];
                }
        }
    }
    __syncthreads();                     // BufA reads done by all; kT written

    // ---------------- phase v ----------------
    STAGE(Xv, BufA);
    __syncthreads();                     // BufA(Xv) ready
    ZEROACC();
    COMPUTE(BufA, w16 + 131072);
    __syncthreads();                     // BufA reads done -> BufA free for vT
    {
        const float* bpv = bperm + 512;
#pragma unroll
        for (int mf = 0; mf < 4; ++mf)
#pragma unroll
            for (int r = 0; r < 4; ++r) {
                const int o = wave * 64 + mf * 16 + quad * 4 + r;
                const float bb = bpv[o];
#pragma unroll
                for (int nf = 0; nf < 4; ++nf)
                    BufA[o * KVS + nf * 16 + ln] = (f16)(acc[mf][nf][r] + bb);
            }
    }
    __syncthreads();                     // vT ready (kT ready since phase k)
    {
        // KV per head: C[qd][kd] = sum_l v'[qd][l] * k'[kd][l]
        // (kv_mfma's verified operand/store convention)
#pragma unroll
        for (int hh = 0; hh < 2; ++hh) {
            const int h = wave * 2 + hh;
            f32x4 kvacc[2][2];
#pragma unroll
            for (int ti = 0; ti < 2; ++ti)
#pragma unroll
                for (int tj = 0; tj < 2; ++tj)
#pragma unroll
                    for (int r = 0; r < 4; ++r) kvacc[ti][tj][r] = 0.f;
#pragma unroll
            for (int ks = 0; ks < 2; ++ks) {
                const int kc = ks * 32 + quad * 8;
                f16x8 aV[2], bK[2];
#pragma unroll
                for (int tt = 0; tt < 2; ++tt) {
                    aV[tt] = *(const f16x8*)&BufA[(h * 32 + tt * 16 + ln) * KVS + kc];
                    bK[tt] = *(const f16x8*)&BufB[(h * 32 + tt * 16 + ln) * KVS + kc];
                }
#pragma unroll
                for (int ti = 0; ti < 2; ++ti)
#pragma unroll
                    for (int tj = 0; tj < 2; ++tj)
                        kvacc[ti][tj] = __builtin_amdgcn_mfma_f32_16x16x32_f16(aV[ti], bK[tj], kvacc[ti][tj], 0, 0, 0);
            }
            float* KVp = KVpart + ((size_t)ls * 64 + b * NHEADS + h) * 1024;
#pragma unroll
            for (int ti = 0; ti < 2; ++ti)
#pragma unroll
                for (int tj = 0; tj < 2; ++tj)
#pragma unroll
                    for (int r = 0; r < 4; ++r)
                        KVp[(ti * 16 + quad * 4 + r) * 32 + tj * 16 + ln] = kvacc[ti][tj][r];
        }
    }
    __syncthreads();                     // kT/vT reads done -> BufB free

    // ---------------- phase q ----------------
    STAGE(Xq, BufB);
    __syncthreads();                     // BufB(Xq) ready
    ZEROACC();
    COMPUTE(BufB, w16);
    __syncthreads();                     // BufB reads done -> reuse as Cb
    {
        const float* bpq = bperm;
        float bv_[4][4];
#pragma unroll
        for (int mf = 0; mf < 4; ++mf)
#pragma unroll
            for (int r = 0; r < 4; ++r)
                bv_[mf][r] = bpq[wave * 64 + mf * 16 + quad * 4 + r];
#pragma unroll
        for (int mf = 0; mf < 4; ++mf)
#pragma unroll
            for (int nf = 0; nf < 4; ++nf) {
                f16x4 w;
#pragma unroll
                for (int r = 0; r < 4; ++r) w[r] = (f16)(acc[mf][nf][r] + bv_[mf][r]);
                *(f16x4*)&BufB[(nf * 16 + ln) * XSTR + wave * 64 + mf * 16 + quad * 4] = w;
            }
        __syncthreads();
        const int rw = tid >> 3, sg = tid & 7;
#pragma unroll
        for (int u = 0; u < 8; ++u) {
            const int row = (u & 1) * 32 + rw;
            const int col = (u >> 1) * 64 + sg * 8;
            *(f16x8*)(qp + ((size_t)(b * SEQL + l0 + row)) * 256 + col) =
                *(const f16x8*)&BufB[row * XSTR + col];
        }
    }
#undef LOADX
#undef STOREB
#undef STAGE
#undef ZEROACC
#undef COMPUTE
}

// ---------------------------------------------------------------------------
// kv_reduce v3: sum the 64 l-slice partials and emit KVaug in f16
// fragment-linear B-operand layout (as r12, verified).
// ---------------------------------------------------------------------------
__global__ __launch_bounds__(256) void kv_reduce(
    const float* __restrict__ KVpart, const float* __restrict__ ksum_part,
    f16* __restrict__ KVaug) {
    const int bh = blockIdx.x;
    const int t = threadIdx.x;
    const float* src = KVpart + (size_t)bh * 1024 + t * 4;
    float ax = 0.f, ay = 0.f, az = 0.f, aw = 0.f;
#pragma unroll
    for (int s = 0; s < NSPLIT; ++s) {
        float4 p = *(const float4*)(src + (size_t)s * 65536);
        ax += p.x; ay += p.y; az += p.z; aw += p.w;
    }
    {
        const int qd = t >> 3, c = t & 7;
        const int nf = qd >> 4, lnq = qd & 15, quad = c >> 1;
        const int lane = quad * 16 + lnq;
        f16x4 w4;
        w4[0] = (f16)ax; w4[1] = (f16)ay; w4[2] = (f16)az; w4[3] = (f16)aw;
        *(f16x4*)&KVaug[((size_t)(bh * 3) + nf) * 512 + lane * 8 + (c & 1) * 4] = w4;
    }
    // nf=2 fragment: row 32 = ksum, rows 33..47 = 0
    f16* aug2 = KVaug + ((size_t)(bh * 3) + 2) * 512;
    if (t < 32) {
        float ss = 0.f;
#pragma unroll
        for (int s = 0; s < NSPLIT; ++s)
            ss += ksum_part[((size_t)s * 64 + bh) * 32 + t];
        aug2[(size_t)((t >> 3) * 16) * 8 + (t & 7)] = (f16)ss;   // lane=(t>>3)*16 (ln=0)
    }
    {
        const int lane2 = t >> 2;
        if ((lane2 & 15) != 0) {
            f16x2 z; z[0] = (f16)0.f; z[1] = (f16)0.f;
            *(f16x2*)&aug2[t * 2] = z;
        }
    }
}

// ---------------------------------------------------------------------------
// Fused attention + output projection v3 (r12, verified): B-fragments load
// directly from KVaug; LDS 35.8 KB => 4 blocks/CU; lane-linear xs staging;
// wfrag Wm; f32 LDS-bounce output epilogue.
// ---------------------------------------------------------------------------
__global__ __launch_bounds__(256) void attn_out_kernel(
    const f16* __restrict__ qp, const f16* __restrict__ KVaug,
    const f16* __restrict__ wm16, const float* __restrict__ bm,
    float* __restrict__ out) {
    __shared__ __align__(16) f16 xs[64 * 264];        // 33792 B
    __shared__ float dens[8][64];                     // 2048 B
    const int b = blockIdx.y;
    const int l0 = blockIdx.x * 64;
    const int t = threadIdx.x;
    const int wave = t >> 6, lane = t & 63;
    const int ln = lane & 15, quad = lane >> 4;

    {
        const int rbase = t >> 5, ch = (t & 31) * 8;
        const f16* qr = qp + ((size_t)(b * SEQL + l0 + rbase)) * 256 + ch;
        f16* dst = &xs[rbase * 264 + ch];
#pragma unroll
        for (int p = 0; p < 8; ++p) {
            f16x8 v = *(const f16x8*)(qr + (size_t)(p * 8) * 256);
            f16x8 w;
#pragma unroll
            for (int j = 0; j < 8; ++j) w[j] = (f16)elu1((float)v[j]);
            *(f16x8*)(dst + p * 8 * 264) = w;
        }
    }
    __syncthreads();
#pragma unroll
    for (int hh = 0; hh < 2; ++hh) {
        const int h = wave * 2 + hh;
        const f16* kvb = KVaug + ((size_t)((b * NHEADS + h) * 3)) * 512 + lane * 8;
        f16x8 a_s[4], b_s[3];
#pragma unroll
        for (int nf = 0; nf < 3; ++nf)
            b_s[nf] = *(const f16x8*)(kvb + nf * 512);
#pragma unroll
        for (int mf = 0; mf < 4; ++mf)
            a_s[mf] = *(const f16x8*)&xs[(mf * 16 + ln) * 264 + h * 32 + quad * 8];
        f32x4 C[4][3];
#pragma unroll
        for (int mf = 0; mf < 4; ++mf)
#pragma unroll
            for (int nf = 0; nf < 3; ++nf) {
#pragma unroll
                for (int r = 0; r < 4; ++r) C[mf][nf][r] = 0.f;
                C[mf][nf] = __builtin_amdgcn_mfma_f32_16x16x32_f16(a_s[mf], b_s[nf], C[mf][nf], 0, 0, 0);
            }
        if (ln == 0) {
#pragma unroll
            for (int mf = 0; mf < 4; ++mf)
#pragma unroll
                for (int r = 0; r < 4; ++r)
                    dens[h][mf * 16 + quad * 4 + r] = C[mf][2][r];
        }
        __syncthreads();
#pragma unroll
        for (int mf = 0; mf < 4; ++mf)
#pragma unroll
            for (int r = 0; r < 4; ++r) {
                const int l = mf * 16 + quad * 4 + r;
                const float rd = __builtin_amdgcn_rcpf(dens[h][l] + EPS);
#pragma unroll
                for (int nf = 0; nf < 2; ++nf)
                    xs[l * 264 + h * 32 + nf * 16 + ln] = (f16)(C[mf][nf][r] * rd);
            }
        __syncthreads();
    }
    // phase2: main GEMM, A = Wm via wfrag, B = xs
    f32x4 acc[4][4];
#pragma unroll
    for (int mf = 0; mf < 4; ++mf)
#pragma unroll
        for (int nf = 0; nf < 4; ++nf)
#pragma unroll
            for (int r = 0; r < 4; ++r) acc[mf][nf][r] = 0.f;
    const f16* Wl = wm16 + lane * 8;
    f16x8 afc[4], afn[4];
#pragma unroll
    for (int mf = 0; mf < 4; ++mf)
        afc[mf] = *(const f16x8*)(Wl + (wave * 32 + mf * 8 + 0) * 512);
#pragma unroll
    for (int it = 0; it < 8; ++it) {
        const int k0 = it * 32;
        if (it < 7) {
#pragma unroll
            for (int mf = 0; mf < 4; ++mf)
                afn[mf] = *(const f16x8*)(Wl + (wave * 32 + mf * 8 + it + 1) * 512);
        }
        f16x8 bf[4];
#pragma unroll
        for (int nf = 0; nf < 4; ++nf)
            bf[nf] = *(const f16x8*)&xs[(nf * 16 + ln) * 264 + k0 + quad * 8];
#pragma unroll
        for (int mf = 0; mf < 4; ++mf)
#pragma unroll
            for (int nf = 0; nf < 4; ++nf)
                acc[mf][nf] = __builtin_amdgcn_mfma_f32_16x16x32_f16(afc[mf], bf[nf], acc[mf][nf], 0, 0, 0);
#pragma unroll
        for (int mf = 0; mf < 4; ++mf) afc[mf] = afn[mf];
    }
    float* Of = (float*)xs;
    __syncthreads();
#pragma unroll
    for (int p = 0; p < 2; ++p) {
        if ((wave >> 1) == p) {
            const int rb = (wave & 1) * 64;
#pragma unroll
            for (int mf = 0; mf < 4; ++mf)
#pragma unroll
                for (int r = 0; r < 4; ++r) {
                    const int o = wave * 64 + mf * 16 + quad * 4 + r;
                    const float bb = bm[o];
                    const int row = rb + mf * 16 + quad * 4 + r;
#pragma unroll
                    for (int nf = 0; nf < 4; ++nf)
                        Of[row * 66 + nf * 16 + ln] = acc[mf][nf][r] + bb;
                }
        }
        __syncthreads();
        {
            const int rw = t >> 4, lc = (t & 15) * 4;
#pragma unroll
            for (int rnd = 0; rnd < 8; ++rnd) {
                const int row = rnd * 16 + rw;
                float4 v4 = *(const float4*)&Of[row * 66 + lc];
                *(float4*)(out + ((size_t)(b * D_MODEL + p * 128 + row)) * SEQL + l0 + lc) = v4;
            }
        }
        __syncthreads();
    }
}

// ---------------------------------------------------------------------------
extern "C" void kernel_launch(void* const* d_in, const int* in_sizes, int n_in,
                              void* d_out, int out_size, void* d_ws, size_t ws_size,
                              hipStream_t stream) {
    const float* query = (const float*)d_in[0];
    const float* key_  = (const float*)d_in[1];
    const float* value = (const float*)d_in[2];
    const float* Wq = (const float*)d_in[3];
    const float* bq = (const float*)d_in[4];
    const float* Wk = (const float*)d_in[5];
    const float* bk = (const float*)d_in[6];
    const float* Wv = (const float*)d_in[7];
    const float* bv = (const float*)d_in[8];
    const float* Wm = (const float*)d_in[9];
    const float* bm = (const float*)d_in[10];

    char* w = (char*)d_ws;
    f16*   w16    = (f16*)w;                        // 524288 B
    float* bperm  = (float*)(w + 524288);           // 3072 B (pad to 528384)
    float* KVpart = (float*)(w + 528384);           // 64*64*1024*4 = 16777216 B
    float* ksum_p = (float*)(w + 17305600);         // 64*64*32*4 = 524288 B
    f16*   KVaug  = (f16*)(w + 17829888);           // 64*3*512*2 = 196608 B
    f16*   qp     = (f16*)(w + 18026496);           // 16.7 MB

    prep_kernel<<<1025, 256, 0, stream>>>(Wq, Wk, Wv, Wm, bq, bk, bv, w16, bperm);

    gemm_fused<<<dim3(SEQL / 64, 1, BATCH), 256, 0, stream>>>(
        query, key_, value, w16, bperm, qp, KVpart, ksum_p);

    kv_reduce<<<dim3(BATCH * NHEADS), 256, 0, stream>>>(KVpart, ksum_p, KVaug);

    attn_out_kernel<<<dim3(SEQL / 64, BATCH), 256, 0, stream>>>(
        qp, KVaug, w16 + 3 * 65536, bm, (float*)d_out);
}